// Round 2
// baseline (196.664 us; speedup 1.0000x reference)
//
#include <hip/hip_runtime.h>

// entmax-1.5 n-section loss, decoupled 3-kernel design.
//
// X:(n=4096, c=32000) fp32. Xs = X/2; tau in [rowmax-1, rowmax] via 9 iters of
// 4-section search on f(tau) = sum relu(Xs-tau)^2 - 1. Since every evaluated
// tau >= rowmax-1, only elements with Xs > rowmax-1 ever contribute.
//
// pass1:  2 blocks/row (half-row each, 16 data VGPRs -> no spill). Computes
//         half-row max, gathers superset {Xs > halfmax-1} to global ws.
//         (halfmax <= rowmax so this is a superset; extras contribute 0.)
// search: one wave per row; 9-iter search + final sums over ~900 L1-resident
//         candidates. Fully parallel across 4096 rows -- no serial tail.
// reduce: mean of row losses.
//
// Fallbacks: per-row overflow -> wave re-scans the full row from global;
// ws too small -> proven monolithic kernel (round-1, passed absmax 0.0).

#define NTHR   1024
#define NITER  9
#define SUBCAP 3072   // per half-row candidate capacity (expected ~460, max ~1900)
#define CAP    8192   // monolithic-fallback LDS capacity

// ---------------------------------------------------------------------------
// pass1: half-row streamer + candidate gather
// ---------------------------------------------------------------------------
__global__ __launch_bounds__(NTHR, 8)
void pass1_kernel(const float* __restrict__ X,
                  float* __restrict__ maxes,
                  int*   __restrict__ counts,
                  float* __restrict__ cand,
                  int c) {
    const int sb   = blockIdx.x;      // sub-block = row*2 + half
    const int r    = sb >> 1;
    const int h    = sb & 1;
    const int tid  = threadIdx.x;
    const int wave = tid >> 6;
    const int lane = tid & 63;

    const int half0 = c >> 1;
    const int start = h ? half0 : 0;
    const int len   = h ? (c - half0) : half0;
    const float* __restrict__ Xh = X + (size_t)r * (size_t)c + start;

    __shared__ float s_red[16];
    __shared__ float s_b;
    __shared__ int   s_cnt;

    // ---- one coalesced pass: load Xs = X/2 into registers ----
    const int len4 = len >> 2;
    float4 v[4];                      // 4*4*1024 = 16384 >= 16000
    #pragma unroll
    for (int k = 0; k < 4; ++k) {
        const int i4 = tid + k * NTHR;
        if (i4 < len4) {
            const float4 t = ((const float4*)Xh)[i4];
            v[k].x = 0.5f * t.x; v[k].y = 0.5f * t.y;
            v[k].z = 0.5f * t.z; v[k].w = 0.5f * t.w;
        } else {
            v[k].x = v[k].y = v[k].z = v[k].w = -1e30f;
        }
    }
    float tail = -1e30f;
    const int ti = (len4 << 2) + tid;
    if (ti < len) tail = 0.5f * Xh[ti];

    // ---- half-row max ----
    float m = tail;
    #pragma unroll
    for (int k = 0; k < 4; ++k)
        m = fmaxf(m, fmaxf(fmaxf(v[k].x, v[k].y), fmaxf(v[k].z, v[k].w)));
    #pragma unroll
    for (int off = 32; off > 0; off >>= 1)
        m = fmaxf(m, __shfl_xor(m, off));
    if (lane == 0) s_red[wave] = m;
    if (tid == 0) s_cnt = 0;
    __syncthreads();
    if (tid == 0) {
        float mm = s_red[0];
        for (int i = 1; i < 16; ++i) mm = fmaxf(mm, s_red[i]);
        s_b = mm;
        maxes[sb] = mm;
    }
    __syncthreads();
    const float t0 = s_b - 1.0f;      // local threshold (superset of true set)

    // ---- gather candidates (Xs > t0) to global ----
    int cnt = (tail > t0) ? 1 : 0;
    #pragma unroll
    for (int k = 0; k < 4; ++k)
        cnt += (v[k].x > t0) + (v[k].y > t0) + (v[k].z > t0) + (v[k].w > t0);
    int pos = 0;
    if (cnt > 0) pos = atomicAdd(&s_cnt, cnt);
    float* __restrict__ gc = cand + (size_t)sb * SUBCAP;
    #pragma unroll
    for (int k = 0; k < 4; ++k) {
        if (v[k].x > t0) { if (pos < SUBCAP) gc[pos] = v[k].x; ++pos; }
        if (v[k].y > t0) { if (pos < SUBCAP) gc[pos] = v[k].y; ++pos; }
        if (v[k].z > t0) { if (pos < SUBCAP) gc[pos] = v[k].z; ++pos; }
        if (v[k].w > t0) { if (pos < SUBCAP) gc[pos] = v[k].w; ++pos; }
    }
    if (tail > t0) { if (pos < SUBCAP) gc[pos] = tail; ++pos; }
    __syncthreads();
    if (tid == 0) counts[sb] = s_cnt;  // raw count; search checks overflow
}

// ---------------------------------------------------------------------------
// search: one wave per row over the candidate superset
// ---------------------------------------------------------------------------
__global__ __launch_bounds__(256, 4)
void search_kernel(const float* __restrict__ X,
                   const int*   __restrict__ target,
                   const float* __restrict__ maxes,
                   const int*   __restrict__ counts,
                   const float* __restrict__ cand,
                   float* __restrict__ row_loss,
                   int n, int c) {
    const int wave = threadIdx.x >> 6;
    const int lane = threadIdx.x & 63;
    const int r    = blockIdx.x * 4 + wave;
    if (r >= n) return;

    const float m0 = maxes[2 * r];
    const float m1 = maxes[2 * r + 1];
    const float mx = fmaxf(m0, m1);
    const int   c0 = counts[2 * r];
    const int   c1 = counts[2 * r + 1];
    const float* __restrict__ g0 = cand + (size_t)(2 * r) * SUBCAP;
    const float* __restrict__ g1 = cand + (size_t)(2 * r + 1) * SUBCAP;
    const float* __restrict__ Xr = X + (size_t)r * (size_t)c;

    float lo = mx - 1.0f, hi = mx;
    float S1, SX, S3;

    if (c0 <= SUBCAP && c1 <= SUBCAP) {
        const int total = c0 + c1;
        for (int it = 0; it < NITER; ++it) {
            const float w  = (hi - lo) * 0.25f;
            const float t1 = lo + w, t2 = lo + 2.0f * w, t3 = lo + 3.0f * w;
            float f1 = 0.f, f2 = 0.f, f3 = 0.f;
            for (int i = lane; i < total; i += 64) {
                const float x = (i < c0) ? g0[i] : g1[i - c0];
                const float d1 = fmaxf(x - t1, 0.f); f1 = fmaf(d1, d1, f1);
                const float d2 = fmaxf(x - t2, 0.f); f2 = fmaf(d2, d2, f2);
                const float d3 = fmaxf(x - t3, 0.f); f3 = fmaf(d3, d3, f3);
            }
            #pragma unroll
            for (int off = 32; off > 0; off >>= 1) {
                f1 += __shfl_xor(f1, off);
                f2 += __shfl_xor(f2, off);
                f3 += __shfl_xor(f3, off);
            }
            const int cc = (f1 >= 1.f) + (f2 >= 1.f) + (f3 >= 1.f);
            lo = lo + w * (float)cc;
            hi = lo + w;
        }
        const float tau = 0.5f * (lo + hi);
        S1 = 0.f; SX = 0.f; S3 = 0.f;
        for (int i = lane; i < total; i += 64) {
            const float x = (i < c0) ? g0[i] : g1[i - c0];
            const float d = fmaxf(x - tau, 0.f);
            const float q = d * d;
            S1 += q; SX = fmaf(q, x, SX); S3 = fmaf(q, d, S3);
        }
    } else {
        // overflow fallback (never expected): re-scan the full row
        for (int it = 0; it < NITER; ++it) {
            const float w  = (hi - lo) * 0.25f;
            const float t1 = lo + w, t2 = lo + 2.0f * w, t3 = lo + 3.0f * w;
            float f1 = 0.f, f2 = 0.f, f3 = 0.f;
            for (int i = lane; i < c; i += 64) {
                const float x = 0.5f * Xr[i];
                const float d1 = fmaxf(x - t1, 0.f); f1 = fmaf(d1, d1, f1);
                const float d2 = fmaxf(x - t2, 0.f); f2 = fmaf(d2, d2, f2);
                const float d3 = fmaxf(x - t3, 0.f); f3 = fmaf(d3, d3, f3);
            }
            #pragma unroll
            for (int off = 32; off > 0; off >>= 1) {
                f1 += __shfl_xor(f1, off);
                f2 += __shfl_xor(f2, off);
                f3 += __shfl_xor(f3, off);
            }
            const int cc = (f1 >= 1.f) + (f2 >= 1.f) + (f3 >= 1.f);
            lo = lo + w * (float)cc;
            hi = lo + w;
        }
        const float tau = 0.5f * (lo + hi);
        S1 = 0.f; SX = 0.f; S3 = 0.f;
        for (int i = lane; i < c; i += 64) {
            const float x = 0.5f * Xr[i];
            const float d = fmaxf(x - tau, 0.f);
            const float q = d * d;
            S1 += q; SX = fmaf(q, x, SX); S3 = fmaf(q, d, S3);
        }
    }
    #pragma unroll
    for (int off = 32; off > 0; off >>= 1) {
        S1 += __shfl_xor(S1, off);
        SX += __shfl_xor(SX, off);
        S3 += __shfl_xor(S3, off);
    }
    if (lane == 0) {
        const float omega = (1.f - S3 / (S1 * sqrtf(S1))) * (4.f / 3.f);
        const int tg = target[r];
        row_loss[r] = omega + 2.f * SX / S1 - Xr[tg];
    }
}

// ---------------------------------------------------------------------------
// monolithic fallback (round-1 kernel, passed absmax 0.0) — ws-too-small path
// ---------------------------------------------------------------------------
#define VPT4 8
__global__ __launch_bounds__(NTHR, 8)
void entmax_row_kernel(const float* __restrict__ X,
                       const int* __restrict__ target,
                       float* __restrict__ row_loss,
                       int c) {
    const int r    = blockIdx.x;
    const int tid  = threadIdx.x;
    const int wave = tid >> 6;
    const int lane = tid & 63;
    const float* __restrict__ Xr = X + (size_t)r * (size_t)c;

    __shared__ float s_red[16];
    __shared__ float s_r3[3][16];
    __shared__ float s_bcast[4];
    __shared__ int   s_cnt;
    __shared__ float candl[CAP];

    const int c4 = c >> 2;
    float4 v[VPT4];
    #pragma unroll
    for (int k = 0; k < VPT4; ++k) {
        const int i4 = tid + k * NTHR;
        if (i4 < c4) {
            const float4 t4 = ((const float4*)Xr)[i4];
            v[k].x = 0.5f * t4.x; v[k].y = 0.5f * t4.y;
            v[k].z = 0.5f * t4.z; v[k].w = 0.5f * t4.w;
        } else {
            v[k].x = v[k].y = v[k].z = v[k].w = -1e30f;
        }
    }
    float tail = -1e30f;
    const int ti = (c4 << 2) + tid;
    if (ti < c) tail = 0.5f * Xr[ti];

    float m = tail;
    #pragma unroll
    for (int k = 0; k < VPT4; ++k)
        m = fmaxf(m, fmaxf(fmaxf(v[k].x, v[k].y), fmaxf(v[k].z, v[k].w)));
    #pragma unroll
    for (int off = 32; off > 0; off >>= 1)
        m = fmaxf(m, __shfl_xor(m, off));
    if (lane == 0) s_red[wave] = m;
    if (tid == 0) s_cnt = 0;
    __syncthreads();
    if (tid == 0) {
        float mm = s_red[0];
        for (int i = 1; i < 16; ++i) mm = fmaxf(mm, s_red[i]);
        s_bcast[0] = mm;
    }
    __syncthreads();
    const float mx = s_bcast[0];
    const float t0 = mx - 1.0f;

    int cnt = (tail > t0) ? 1 : 0;
    #pragma unroll
    for (int k = 0; k < VPT4; ++k)
        cnt += (v[k].x > t0) + (v[k].y > t0) + (v[k].z > t0) + (v[k].w > t0);
    int pos = 0;
    if (cnt > 0) pos = atomicAdd(&s_cnt, cnt);
    #pragma unroll
    for (int k = 0; k < VPT4; ++k) {
        if (v[k].x > t0) { if (pos < CAP) candl[pos] = v[k].x; ++pos; }
        if (v[k].y > t0) { if (pos < CAP) candl[pos] = v[k].y; ++pos; }
        if (v[k].z > t0) { if (pos < CAP) candl[pos] = v[k].z; ++pos; }
        if (v[k].w > t0) { if (pos < CAP) candl[pos] = v[k].w; ++pos; }
    }
    if (tail > t0) { if (pos < CAP) candl[pos] = tail; ++pos; }
    __syncthreads();
    const int total = s_cnt;

    if (total <= CAP) {
        if (wave == 0) {
            float lo = t0, hi = mx;
            for (int it = 0; it < NITER; ++it) {
                const float w  = (hi - lo) * 0.25f;
                const float t1 = lo + w, t2 = lo + 2.0f * w, t3 = lo + 3.0f * w;
                float f1 = 0.f, f2 = 0.f, f3 = 0.f;
                for (int i = lane; i < total; i += 64) {
                    const float x = candl[i];
                    const float d1 = fmaxf(x - t1, 0.f); f1 = fmaf(d1, d1, f1);
                    const float d2 = fmaxf(x - t2, 0.f); f2 = fmaf(d2, d2, f2);
                    const float d3 = fmaxf(x - t3, 0.f); f3 = fmaf(d3, d3, f3);
                }
                #pragma unroll
                for (int off = 32; off > 0; off >>= 1) {
                    f1 += __shfl_xor(f1, off);
                    f2 += __shfl_xor(f2, off);
                    f3 += __shfl_xor(f3, off);
                }
                const int cc = (f1 >= 1.f) + (f2 >= 1.f) + (f3 >= 1.f);
                lo = lo + w * (float)cc;
                hi = lo + w;
            }
            const float tau = 0.5f * (lo + hi);
            float S1 = 0.f, SX = 0.f, S3 = 0.f;
            for (int i = lane; i < total; i += 64) {
                const float x = candl[i];
                const float d = fmaxf(x - tau, 0.f);
                const float q = d * d;
                S1 += q; SX = fmaf(q, x, SX); S3 = fmaf(q, d, S3);
            }
            #pragma unroll
            for (int off = 32; off > 0; off >>= 1) {
                S1 += __shfl_xor(S1, off);
                SX += __shfl_xor(SX, off);
                S3 += __shfl_xor(S3, off);
            }
            if (lane == 0) {
                const float omega = (1.f - S3 / (S1 * sqrtf(S1))) * (4.f / 3.f);
                const int tg = target[r];
                row_loss[r] = omega + 2.f * SX / S1 - Xr[tg];
            }
        }
    } else {
        float lo = t0, hi = mx;
        for (int it = 0; it < NITER; ++it) {
            const float w  = (hi - lo) * 0.25f;
            const float t1 = lo + w, t2 = lo + 2.0f * w, t3 = lo + 3.0f * w;
            float f1 = 0.f, f2 = 0.f, f3 = 0.f;
            for (int i = tid; i < c; i += NTHR) {
                const float x = 0.5f * Xr[i];
                const float d1 = fmaxf(x - t1, 0.f); f1 = fmaf(d1, d1, f1);
                const float d2 = fmaxf(x - t2, 0.f); f2 = fmaf(d2, d2, f2);
                const float d3 = fmaxf(x - t3, 0.f); f3 = fmaf(d3, d3, f3);
            }
            #pragma unroll
            for (int off = 32; off > 0; off >>= 1) {
                f1 += __shfl_xor(f1, off);
                f2 += __shfl_xor(f2, off);
                f3 += __shfl_xor(f3, off);
            }
            if (lane == 0) { s_r3[0][wave] = f1; s_r3[1][wave] = f2; s_r3[2][wave] = f3; }
            __syncthreads();
            if (tid == 0) {
                float a = 0.f, b = 0.f, g = 0.f;
                for (int i = 0; i < 16; ++i) { a += s_r3[0][i]; b += s_r3[1][i]; g += s_r3[2][i]; }
                s_bcast[0] = a; s_bcast[1] = b; s_bcast[2] = g;
            }
            __syncthreads();
            const int cc = (s_bcast[0] >= 1.f) + (s_bcast[1] >= 1.f) + (s_bcast[2] >= 1.f);
            lo = lo + w * (float)cc;
            hi = lo + w;
        }
        const float tau = 0.5f * (lo + hi);
        float S1 = 0.f, SX = 0.f, S3 = 0.f;
        for (int i = tid; i < c; i += NTHR) {
            const float x = 0.5f * Xr[i];
            const float d = fmaxf(x - tau, 0.f);
            const float q = d * d;
            S1 += q; SX = fmaf(q, x, SX); S3 = fmaf(q, d, S3);
        }
        #pragma unroll
        for (int off = 32; off > 0; off >>= 1) {
            S1 += __shfl_xor(S1, off);
            SX += __shfl_xor(SX, off);
            S3 += __shfl_xor(S3, off);
        }
        if (lane == 0) { s_r3[0][wave] = S1; s_r3[1][wave] = SX; s_r3[2][wave] = S3; }
        __syncthreads();
        if (tid == 0) {
            float a = 0.f, b = 0.f, g = 0.f;
            for (int i = 0; i < 16; ++i) { a += s_r3[0][i]; b += s_r3[1][i]; g += s_r3[2][i]; }
            const float omega = (1.f - g / (a * sqrtf(a))) * (4.f / 3.f);
            const int tg = target[r];
            row_loss[r] = omega + 2.f * b / a - Xr[tg];
        }
    }
}

// ---------------------------------------------------------------------------
__global__ __launch_bounds__(NTHR)
void reduce_mean_kernel(const float* __restrict__ vv, float* __restrict__ out, int n) {
    __shared__ float s_red[16];
    float s = 0.f;
    for (int i = threadIdx.x; i < n; i += NTHR) s += vv[i];
    #pragma unroll
    for (int off = 32; off > 0; off >>= 1) s += __shfl_xor(s, off);
    const int wave = threadIdx.x >> 6;
    const int lane = threadIdx.x & 63;
    if (lane == 0) s_red[wave] = s;
    __syncthreads();
    if (threadIdx.x == 0) {
        float t = 0.f;
        for (int i = 0; i < 16; ++i) t += s_red[i];
        out[0] = t / (float)n;
    }
}

extern "C" void kernel_launch(void* const* d_in, const int* in_sizes, int n_in,
                              void* d_out, int out_size, void* d_ws, size_t ws_size,
                              hipStream_t stream) {
    const float* X      = (const float*)d_in[0];
    const int*   target = (const int*)d_in[1];
    float*       out    = (float*)d_out;

    const int n = in_sizes[1];
    const int c = in_sizes[0] / n;

    char* ws = (char*)d_ws;
    size_t off = 0;
    float* row_loss = (float*)(ws + off); off += (((size_t)n * 4) + 255) & ~(size_t)255;
    float* maxes    = (float*)(ws + off); off += (((size_t)2 * n * 4) + 255) & ~(size_t)255;
    int*   counts   = (int*)  (ws + off); off += (((size_t)2 * n * 4) + 255) & ~(size_t)255;
    float* cand     = (float*)(ws + off); off += (size_t)2 * n * SUBCAP * 4;

    if (off <= ws_size && (c % 8) == 0) {
        pass1_kernel<<<2 * n, NTHR, 0, stream>>>(X, maxes, counts, cand, c);
        search_kernel<<<(n + 3) / 4, 256, 0, stream>>>(X, target, maxes, counts, cand,
                                                       row_loss, n, c);
    } else {
        entmax_row_kernel<<<n, NTHR, 0, stream>>>(X, target, row_loss, c);
    }
    reduce_mean_kernel<<<1, NTHR, 0, stream>>>(row_loss, out, n);
}